// Round 1
// baseline (682.801 us; speedup 1.0000x reference)
//
#include <hip/hip_runtime.h>

#define N 2048
#define D 64
#define BH 16
#define NWORDS 3126  // ceil(100001 / 32) words for bitmap over r in [0,100000]

// ---------------------------------------------------------------------------
// Kernel 1: scores = (q * 0.125) @ k^T   per head; written into attn buffer.
// 64x64 C-tile per block, 256 threads, 4x4 register blocking, K-dim = 64.
// ---------------------------------------------------------------------------
__global__ __launch_bounds__(256) void qk_kernel(const float* __restrict__ q,
                                                 const float* __restrict__ k,
                                                 float* __restrict__ attn) {
  __shared__ __align__(16) float QT[D][68];  // [d][row], pad 68 to break conflicts
  __shared__ __align__(16) float KT[D][68];  // [d][col]
  const int h = blockIdx.z;
  const int row0 = blockIdx.y * 64;
  const int col0 = blockIdx.x * 64;
  const float* qh = q + (size_t)h * N * D;
  const float* kh = k + (size_t)h * N * D;
  const int tid = threadIdx.x;

  // Stage tiles (transposed) — global reads coalesced over d
  for (int idx = tid; idx < 64 * D; idx += 256) {
    int d = idx & 63;
    int r = idx >> 6;
    QT[d][r] = qh[(size_t)(row0 + r) * D + d] * 0.125f;  // exact pre-scale
    KT[d][r] = kh[(size_t)(col0 + r) * D + d];
  }
  __syncthreads();

  const int tc = tid & 15, tr = tid >> 4;
  const int r0 = tr * 4, c0 = tc * 4;
  float acc[4][4] = {};

#pragma unroll 8
  for (int d = 0; d < D; ++d) {
    float4 a = *(const float4*)&QT[d][r0];
    float4 b = *(const float4*)&KT[d][c0];
    float av[4] = {a.x, a.y, a.z, a.w};
    float bv[4] = {b.x, b.y, b.z, b.w};
#pragma unroll
    for (int i = 0; i < 4; ++i)
#pragma unroll
      for (int j = 0; j < 4; ++j) acc[i][j] = fmaf(av[i], bv[j], acc[i][j]);
  }

  float* outp = attn + ((size_t)h * N + row0) * N + col0;
#pragma unroll
  for (int i = 0; i < 4; ++i) {
    float4 vres = make_float4(acc[i][0], acc[i][1], acc[i][2], acc[i][3]);
    *(float4*)&outp[(size_t)(r0 + i) * N + c0] = vres;
  }
}

// ---------------------------------------------------------------------------
// Kernel 2: per-row transform, one block (256 thr) per row of 2048 scores.
// max -> exp -> round(1e5) -> bitmap dedup-sum -> attn_p = x/sum (in place).
// ---------------------------------------------------------------------------
__global__ __launch_bounds__(256) void row_kernel(float* __restrict__ attn) {
  __shared__ unsigned bm[NWORDS];
  __shared__ float wred[4];

  const size_t row = blockIdx.x;
  float4* rp = (float4*)(attn + row * (size_t)N);
  const int t = threadIdx.x;
  const int lane = t & 63;
  const int wave = t >> 6;

  float4 v0 = rp[t];
  float4 v1 = rp[t + 256];
  float x[8] = {v0.x, v0.y, v0.z, v0.w, v1.x, v1.y, v1.z, v1.w};

  // ---- block max ----
  float m = x[0];
#pragma unroll
  for (int j = 1; j < 8; ++j) m = fmaxf(m, x[j]);
#pragma unroll
  for (int o = 32; o > 0; o >>= 1) m = fmaxf(m, __shfl_xor(m, o, 64));
  if (lane == 0) wred[wave] = m;
  __syncthreads();
  m = fmaxf(fmaxf(wred[0], wred[1]), fmaxf(wred[2], wred[3]));
  __syncthreads();

  // ---- clear bitmap ----
  for (int i = t; i < NWORDS; i += 256) bm[i] = 0u;
  __syncthreads();

  // ---- exp/round + dedup-sum via test-and-set ----
  float xr[8];
  float lsum = 0.0f;
#pragma unroll
  for (int j = 0; j < 8; ++j) {
    float ex = expf(x[j] - m);              // <= 1.0
    float rf = rintf(ex * 100000.0f);       // round-half-even, exact int in fp32
    float xv = rf / 100000.0f;              // match reference's fp32 divide
    xr[j] = xv;
    int ri = (int)rf;                       // 0..100000
    unsigned mask = 1u << (ri & 31);
    unsigned old = atomicOr(&bm[ri >> 5], mask);
    if (!(old & mask)) lsum += xv;          // count each distinct value once
  }

  // ---- block sum ----
#pragma unroll
  for (int o = 32; o > 0; o >>= 1) lsum += __shfl_xor(lsum, o, 64);
  if (lane == 0) wred[wave] = lsum;
  __syncthreads();
  const float total = wred[0] + wred[1] + wred[2] + wred[3];

  // ---- normalize + write back ----
  float4 p0 = make_float4(xr[0] / total, xr[1] / total, xr[2] / total, xr[3] / total);
  float4 p1 = make_float4(xr[4] / total, xr[5] / total, xr[6] / total, xr[7] / total);
  rp[t] = p0;
  rp[t + 256] = p1;
}

// ---------------------------------------------------------------------------
// Kernel 3: out = attn_p @ v   per head.  64-row x 64-col tile per block.
// ---------------------------------------------------------------------------
__global__ __launch_bounds__(256) void pv_kernel(const float* __restrict__ attn,
                                                 const float* __restrict__ v,
                                                 float* __restrict__ outp) {
  __shared__ __align__(16) float PT[64][68];  // [m][row]
  __shared__ __align__(16) float VS[64][68];  // [m][col]
  const int h = blockIdx.y;
  const int row0 = blockIdx.x * 64;
  const float* ph = attn + (size_t)h * N * N;
  const float* vh = v + (size_t)h * N * D;
  const int tid = threadIdx.x;
  const int tc = tid & 15, tr = tid >> 4;
  const int r0 = tr * 4, c0 = tc * 4;
  float acc[4][4] = {};

  for (int m0 = 0; m0 < N; m0 += 64) {
    __syncthreads();
    for (int idx = tid; idx < 4096; idx += 256) {
      int a = idx & 63;
      int b = idx >> 6;
      PT[a][b] = ph[(size_t)(row0 + b) * N + m0 + a];  // coalesced over a (m)
      VS[b][a] = vh[(size_t)(m0 + b) * D + a];         // coalesced over a (c)
    }
    __syncthreads();
#pragma unroll 8
    for (int m = 0; m < 64; ++m) {
      float4 a = *(const float4*)&PT[m][r0];
      float4 b = *(const float4*)&VS[m][c0];
      float av[4] = {a.x, a.y, a.z, a.w};
      float bv[4] = {b.x, b.y, b.z, b.w};
#pragma unroll
      for (int i = 0; i < 4; ++i)
#pragma unroll
        for (int j = 0; j < 4; ++j) acc[i][j] = fmaf(av[i], bv[j], acc[i][j]);
    }
  }

  float* oh = outp + ((size_t)h * N + row0) * D;
#pragma unroll
  for (int i = 0; i < 4; ++i) {
    float4 vres = make_float4(acc[i][0], acc[i][1], acc[i][2], acc[i][3]);
    *(float4*)&oh[(size_t)(r0 + i) * D + c0] = vres;
  }
}

// ---------------------------------------------------------------------------
extern "C" void kernel_launch(void* const* d_in, const int* in_sizes, int n_in,
                              void* d_out, int out_size, void* d_ws, size_t ws_size,
                              hipStream_t stream) {
  const float* q = (const float*)d_in[0];
  const float* k = (const float*)d_in[1];
  const float* v = (const float*)d_in[2];
  float* out = (float*)d_out;
  float* attn = out + (size_t)BH * N * D;  // attn_p region of d_out, used as scratch

  qk_kernel<<<dim3(N / 64, N / 64, BH), 256, 0, stream>>>(q, k, attn);
  row_kernel<<<dim3(BH * N), 256, 0, stream>>>(attn);
  pv_kernel<<<dim3(N / 64, BH), 256, 0, stream>>>(attn, v, out);
}

// Round 2
// 578.033 us; speedup vs baseline: 1.1812x; 1.1812x over previous
//
#include <hip/hip_runtime.h>

#define N 2048
#define D 64
#define BH 16
#define NWORDS 3126  // ceil(100001 / 32) words for bitmap over r in [0,100000]

typedef __bf16 bf16x8 __attribute__((ext_vector_type(8)));
typedef float f32x4 __attribute__((ext_vector_type(4)));

union Bf16x8U {
  bf16x8 v;
  __bf16 e[8];
  unsigned short us[8];
};

// Split 8 fp32 (two float4) into hi/lo bf16 fragments: f = hi + lo + O(2^-16 f)
static __device__ inline void split8(const float4& a, const float4& b,
                                     bf16x8& hi, bf16x8& lo) {
  float f[8] = {a.x, a.y, a.z, a.w, b.x, b.y, b.z, b.w};
  Bf16x8U h, l;
#pragma unroll
  for (int i = 0; i < 8; ++i) {
    __bf16 hb = (__bf16)f[i];
    h.e[i] = hb;
    l.e[i] = (__bf16)(f[i] - (float)hb);
  }
  hi = h.v;
  lo = l.v;
}

// ---------------------------------------------------------------------------
// Kernel 1: scores = (q*0.125) @ k^T via split-precision bf16 MFMA.
// Block = 256 thr (4 waves), C tile 64x64. Wave w: rows w*16..w*16+15, 4
// col-tiles of 16. A/B frags loaded straight from global (contiguous 8-float
// runs per lane), no LDS.
// ---------------------------------------------------------------------------
__global__ __launch_bounds__(256) void qk_kernel(const float* __restrict__ q,
                                                 const float* __restrict__ k,
                                                 float* __restrict__ attn) {
  const int h = blockIdx.z;
  const int row0 = blockIdx.y * 64;
  const int col0 = blockIdx.x * 64;
  const float* qh = q + (size_t)h * N * D;
  const float* kh = k + (size_t)h * N * D;
  const int tid = threadIdx.x;
  const int wave = tid >> 6;
  const int lane = tid & 63;
  const int m = lane & 15;
  const int quad = lane >> 4;

  // A fragments: q rows (row0 + wave*16 + m), K chunks 0-31 and 32-63
  const float* qrow = qh + (size_t)(row0 + wave * 16 + m) * D + quad * 8;
  float4 a00 = *(const float4*)(qrow);
  float4 a01 = *(const float4*)(qrow + 4);
  float4 a10 = *(const float4*)(qrow + 32);
  float4 a11 = *(const float4*)(qrow + 36);
  const float s = 0.125f;  // 1/TEMPERATURE, exact
  a00.x *= s; a00.y *= s; a00.z *= s; a00.w *= s;
  a01.x *= s; a01.y *= s; a01.z *= s; a01.w *= s;
  a10.x *= s; a10.y *= s; a10.z *= s; a10.w *= s;
  a11.x *= s; a11.y *= s; a11.z *= s; a11.w *= s;
  bf16x8 ahi0, alo0, ahi1, alo1;
  split8(a00, a01, ahi0, alo0);
  split8(a10, a11, ahi1, alo1);

  float* outbase = attn + ((size_t)h * N) * N;

#pragma unroll
  for (int ct = 0; ct < 4; ++ct) {
    const float* krow = kh + (size_t)(col0 + ct * 16 + m) * D + quad * 8;
    float4 b00 = *(const float4*)(krow);
    float4 b01 = *(const float4*)(krow + 4);
    float4 b10 = *(const float4*)(krow + 32);
    float4 b11 = *(const float4*)(krow + 36);
    bf16x8 bhi0, blo0, bhi1, blo1;
    split8(b00, b01, bhi0, blo0);
    split8(b10, b11, bhi1, blo1);

    f32x4 c = {0.f, 0.f, 0.f, 0.f};
    c = __builtin_amdgcn_mfma_f32_16x16x32_bf16(alo0, bhi0, c, 0, 0, 0);
    c = __builtin_amdgcn_mfma_f32_16x16x32_bf16(alo1, bhi1, c, 0, 0, 0);
    c = __builtin_amdgcn_mfma_f32_16x16x32_bf16(ahi0, blo0, c, 0, 0, 0);
    c = __builtin_amdgcn_mfma_f32_16x16x32_bf16(ahi1, blo1, c, 0, 0, 0);
    c = __builtin_amdgcn_mfma_f32_16x16x32_bf16(ahi0, bhi0, c, 0, 0, 0);
    c = __builtin_amdgcn_mfma_f32_16x16x32_bf16(ahi1, bhi1, c, 0, 0, 0);

    // C layout: col = lane&15, row = quad*4 + reg
#pragma unroll
    for (int r = 0; r < 4; ++r) {
      outbase[(size_t)(row0 + wave * 16 + quad * 4 + r) * N + col0 + ct * 16 + m] = c[r];
    }
  }
}

// ---------------------------------------------------------------------------
// Kernel 2: per-row transform, one block (256 thr) per row of 2048 scores.
// max -> exp -> round(1e5) -> bitmap dedup-sum -> attn_p = x/sum (in place).
// ---------------------------------------------------------------------------
__global__ __launch_bounds__(256) void row_kernel(float* __restrict__ attn) {
  __shared__ unsigned bm[NWORDS];
  __shared__ float wred[4];

  const size_t row = blockIdx.x;
  float4* rp = (float4*)(attn + row * (size_t)N);
  const int t = threadIdx.x;
  const int lane = t & 63;
  const int wave = t >> 6;

  float4 v0 = rp[t];
  float4 v1 = rp[t + 256];
  float x[8] = {v0.x, v0.y, v0.z, v0.w, v1.x, v1.y, v1.z, v1.w};

  // ---- block max ----
  float m = x[0];
#pragma unroll
  for (int j = 1; j < 8; ++j) m = fmaxf(m, x[j]);
#pragma unroll
  for (int o = 32; o > 0; o >>= 1) m = fmaxf(m, __shfl_xor(m, o, 64));
  if (lane == 0) wred[wave] = m;
  __syncthreads();
  m = fmaxf(fmaxf(wred[0], wred[1]), fmaxf(wred[2], wred[3]));
  __syncthreads();

  // ---- clear bitmap ----
  for (int i = t; i < NWORDS; i += 256) bm[i] = 0u;
  __syncthreads();

  // ---- exp/round + dedup-sum via test-and-set ----
  float xr[8];
  float lsum = 0.0f;
#pragma unroll
  for (int j = 0; j < 8; ++j) {
    float ex = expf(x[j] - m);              // <= 1.0
    float rf = rintf(ex * 100000.0f);       // round-half-even, exact int in fp32
    float xv = rf / 100000.0f;              // match reference's fp32 divide
    xr[j] = xv;
    int ri = (int)rf;                       // 0..100000
    unsigned mask = 1u << (ri & 31);
    unsigned old = atomicOr(&bm[ri >> 5], mask);
    if (!(old & mask)) lsum += xv;          // count each distinct value once
  }

  // ---- block sum ----
#pragma unroll
  for (int o = 32; o > 0; o >>= 1) lsum += __shfl_xor(lsum, o, 64);
  if (lane == 0) wred[wave] = lsum;
  __syncthreads();
  const float total = wred[0] + wred[1] + wred[2] + wred[3];

  // ---- normalize + write back ----
  float4 p0 = make_float4(xr[0] / total, xr[1] / total, xr[2] / total, xr[3] / total);
  float4 p1 = make_float4(xr[4] / total, xr[5] / total, xr[6] / total, xr[7] / total);
  rp[t] = p0;
  rp[t + 256] = p1;
}

// ---------------------------------------------------------------------------
// Kernel 3: out = attn_p @ v via split-precision bf16 MFMA.
// Block = 256 thr (4 waves), C tile 32 rows x 64 cols. Wave w: row-tile
// (w&1), col-tiles {2*(w>>1), +1}. v staged in LDS as packed hi|lo uint,
// pitch 65 (B-frag ds_read ~2-way, free).
// ---------------------------------------------------------------------------
__global__ __launch_bounds__(256) void pv_kernel(const float* __restrict__ attn,
                                                 const float* __restrict__ v,
                                                 float* __restrict__ outp) {
  __shared__ unsigned vpack[64 * 65];
  const int h = blockIdx.y;
  const int row0 = blockIdx.x * 32;
  const float* ph = attn + (size_t)h * N * N;
  const float* vh = v + (size_t)h * N * D;
  const int tid = threadIdx.x;
  const int wave = tid >> 6;
  const int lane = tid & 63;
  const int m = lane & 15;
  const int quad = lane >> 4;
  const int rt = wave & 1;          // row-tile within block
  const int cs = (wave >> 1) * 2;   // first col-tile of this wave

  f32x4 acc[2] = {{0.f, 0.f, 0.f, 0.f}, {0.f, 0.f, 0.f, 0.f}};

  const int skk = tid >> 4;          // staging k row (0..15, step 16)
  const int snn = (tid & 15) * 4;    // staging col group

  for (int k0 = 0; k0 < N; k0 += 64) {
    __syncthreads();
    // stage v[k0..k0+63][0..63] as (hi<<16)|lo
#pragma unroll
    for (int i = 0; i < 4; ++i) {
      int kk = skk + i * 16;
      float4 vv = *(const float4*)(vh + (size_t)(k0 + kk) * D + snn);
      float f[4] = {vv.x, vv.y, vv.z, vv.w};
#pragma unroll
      for (int j = 0; j < 4; ++j) {
        __bf16 hb = (__bf16)f[j];
        __bf16 lb = (__bf16)(f[j] - (float)hb);
        unsigned hu = (unsigned)__builtin_bit_cast(unsigned short, hb);
        unsigned lu = (unsigned)__builtin_bit_cast(unsigned short, lb);
        vpack[(size_t)kk * 65 + snn + j] = (hu << 16) | lu;
      }
    }
    __syncthreads();

#pragma unroll
    for (int kc = 0; kc < 2; ++kc) {
      // A fragment from attn row (global, contiguous 8 floats)
      const float* arow = ph + (size_t)(row0 + rt * 16 + m) * N + k0 + kc * 32 + quad * 8;
      float4 a0 = *(const float4*)(arow);
      float4 a1 = *(const float4*)(arow + 4);
      bf16x8 ahi, alo;
      split8(a0, a1, ahi, alo);

#pragma unroll
      for (int cti = 0; cti < 2; ++cti) {
        int n0 = (cs + cti) * 16;
        Bf16x8U bh, bl;
#pragma unroll
        for (int j = 0; j < 8; ++j) {
          unsigned u = vpack[(size_t)(kc * 32 + quad * 8 + j) * 65 + n0 + m];
          bh.us[j] = (unsigned short)(u >> 16);
          bl.us[j] = (unsigned short)(u & 0xffffu);
        }
        acc[cti] = __builtin_amdgcn_mfma_f32_16x16x32_bf16(alo, bh.v, acc[cti], 0, 0, 0);
        acc[cti] = __builtin_amdgcn_mfma_f32_16x16x32_bf16(ahi, bl.v, acc[cti], 0, 0, 0);
        acc[cti] = __builtin_amdgcn_mfma_f32_16x16x32_bf16(ahi, bh.v, acc[cti], 0, 0, 0);
      }
    }
  }

  float* oh = outp + ((size_t)h * N) * D;
#pragma unroll
  for (int cti = 0; cti < 2; ++cti) {
#pragma unroll
    for (int r = 0; r < 4; ++r) {
      oh[(size_t)(row0 + rt * 16 + quad * 4 + r) * D + (cs + cti) * 16 + m] = acc[cti][r];
    }
  }
}

// ---------------------------------------------------------------------------
extern "C" void kernel_launch(void* const* d_in, const int* in_sizes, int n_in,
                              void* d_out, int out_size, void* d_ws, size_t ws_size,
                              hipStream_t stream) {
  const float* q = (const float*)d_in[0];
  const float* k = (const float*)d_in[1];
  const float* v = (const float*)d_in[2];
  float* out = (float*)d_out;
  float* attn = out + (size_t)BH * N * D;  // attn_p region of d_out, used as scratch

  qk_kernel<<<dim3(N / 64, N / 64, BH), 256, 0, stream>>>(q, k, attn);
  row_kernel<<<dim3(BH * N), 256, 0, stream>>>(attn);
  pv_kernel<<<dim3(N / 32, BH), 256, 0, stream>>>(attn, v, out);
}